// Round 1
// baseline (498.908 us; speedup 1.0000x reference)
//
#include <hip/hip_runtime.h>

// Problem constants (reference: B=64, L=1024, D=1280)
#define BB 64
#define LL 1024
#define DD 1280
#define SPLITS 8        // token splits for the pool
#define CHUNK 128       // ceil(1023 / 8)
#define NCOL 5          // column chunks of 256 (5*256 = 1280)

// ---------------------------------------------------------------------------
// Kernel 1: ragged partial sum pool.
// grid = (SPLITS, B), block = 320 threads (5 waves). Thread t owns float4 #t
// of each 1280-float row; one block iteration reads exactly one row (5120 B),
// fully coalesced 16 B/lane. Partials written to P[s][b][d] (zeros if this
// split is past pool_len, so no pre-zeroing of ws is needed).
// ---------------------------------------------------------------------------
__global__ __launch_bounds__(320) void pool_partial(
    const float* __restrict__ prev, const int* __restrict__ lengths,
    float* __restrict__ P) {
  const int s = blockIdx.x;
  const int b = blockIdx.y;
  const int t = threadIdx.x;  // [0, 320)

  const int pool_len = lengths[b] + 2;     // in [2, 1023]
  const int l0 = s * CHUNK;
  const int l1 = min(pool_len, l0 + CHUNK);

  float4 acc = make_float4(0.f, 0.f, 0.f, 0.f);
  const float* base = prev + (size_t)b * LL * DD + 4 * t;
#pragma unroll 4
  for (int l = l0; l < l1; ++l) {
    const float4 v = *(const float4*)(base + (size_t)l * DD);
    acc.x += v.x; acc.y += v.y; acc.z += v.z; acc.w += v.w;
  }
  float4* dst = (float4*)(P + ((size_t)s * BB + b) * DD) + t;
  *dst = acc;  // unconditional: inactive splits write zeros
}

// ---------------------------------------------------------------------------
// Kernel 2: embedding -> relu(emb @ W + bias) .* cls_w, block-reduced.
// grid = (NCOL, B), block = 256. Stage emb[b,:] in LDS (sum 8 partials,
// divide by pool_len). Each thread computes one output column's dot product;
// W reads are coalesced across lanes (consecutive cols). LDS reads broadcast
// (all lanes read the same emb[d]) -> conflict-free.
// ---------------------------------------------------------------------------
__global__ __launch_bounds__(256) void gemm_relu_partial(
    const float* __restrict__ P, const int* __restrict__ lengths,
    const float* __restrict__ W, const float* __restrict__ bias,
    const float* __restrict__ cls_w, float* __restrict__ Q) {
  __shared__ float emb[DD];
  __shared__ float red[4];

  const int c = blockIdx.x;
  const int b = blockIdx.y;
  const int t = threadIdx.x;

  const float inv = 1.0f / (float)(lengths[b] + 2);
  for (int d = t; d < DD; d += 256) {
    float s = 0.f;
#pragma unroll
    for (int k = 0; k < SPLITS; ++k) s += P[((size_t)k * BB + b) * DD + d];
    emb[d] = s * inv;
  }
  __syncthreads();

  const int col = c * 256 + t;
  float acc = bias[col];
#pragma unroll 8
  for (int d = 0; d < DD; ++d) {
    acc = fmaf(emb[d], W[(size_t)d * DD + col], acc);
  }
  float v = fmaxf(acc, 0.f) * cls_w[col];

  // 256-thread reduction: wave64 shuffle, then cross-wave via LDS.
#pragma unroll
  for (int off = 32; off > 0; off >>= 1) v += __shfl_down(v, off);
  const int lane = t & 63;
  const int wave = t >> 6;
  if (lane == 0) red[wave] = v;
  __syncthreads();
  if (t == 0) Q[b * NCOL + c] = red[0] + red[1] + red[2] + red[3];
}

// ---------------------------------------------------------------------------
// Kernel 3: out[b] = sum_c Q[b][c] + cls_b
// ---------------------------------------------------------------------------
__global__ __launch_bounds__(64) void final_out(
    const float* __restrict__ Q, const float* __restrict__ cls_b,
    float* __restrict__ out) {
  const int b = threadIdx.x;
  if (b < BB) {
    float s = cls_b[0];
#pragma unroll
    for (int c = 0; c < NCOL; ++c) s += Q[b * NCOL + c];
    out[b] = s;
  }
}

extern "C" void kernel_launch(void* const* d_in, const int* in_sizes, int n_in,
                              void* d_out, int out_size, void* d_ws, size_t ws_size,
                              hipStream_t stream) {
  const float* prev    = (const float*)d_in[0];  // [B, L, D] f32
  const int*   lengths = (const int*)d_in[1];    // [B] i32
  const float* dense_w = (const float*)d_in[2];  // [D, D] f32
  const float* dense_b = (const float*)d_in[3];  // [D] f32
  const float* cls_w   = (const float*)d_in[4];  // [D] f32
  const float* cls_b   = (const float*)d_in[5];  // [1] f32
  float* out = (float*)d_out;                    // [B] f32

  // Workspace layout: P [SPLITS*B*D] floats, then Q [B*NCOL] floats (~2.62 MB).
  float* P = (float*)d_ws;
  float* Q = P + (size_t)SPLITS * BB * DD;

  pool_partial<<<dim3(SPLITS, BB), 320, 0, stream>>>(prev, lengths, P);
  gemm_relu_partial<<<dim3(NCOL, BB), 256, 0, stream>>>(P, lengths, dense_w,
                                                        dense_b, cls_w, Q);
  final_out<<<1, 64, 0, stream>>>(Q, cls_b, out);
}

// Round 2
// 474.410 us; speedup vs baseline: 1.0516x; 1.0516x over previous
//
#include <hip/hip_runtime.h>

// Problem constants (reference: B=64, L=1024, D=1280)
#define BB 64
#define LL 1024
#define DD 1280
#define SPLITS 16       // token splits for the pool
#define CHUNK 64        // L / SPLITS
#define CC 20           // column chunks of 64 (20*64 = 1280)
#define BG 16           // b-groups of 4 (16*4 = 64)

// ---------------------------------------------------------------------------
// Kernel 1: ragged partial sum pool.
// grid = (SPLITS, B), block = 320 threads (5 waves). Thread t owns float4 #t
// of each 1280-float row; one block iteration reads one full row (5120 B),
// fully coalesced 16 B/lane. Inactive splits write zeros (no ws pre-zeroing
// needed). 1024 blocks -> 4 blocks/CU -> 20 waves/CU for latency hiding.
// ---------------------------------------------------------------------------
__global__ __launch_bounds__(320) void pool_partial(
    const float* __restrict__ prev, const int* __restrict__ lengths,
    float* __restrict__ P) {
  const int s = blockIdx.x;
  const int b = blockIdx.y;
  const int t = threadIdx.x;  // [0, 320)

  const int pool_len = lengths[b] + 2;  // in [2, 1023]
  const int l0 = s * CHUNK;
  const int l1 = min(pool_len, l0 + CHUNK);

  float4 acc = make_float4(0.f, 0.f, 0.f, 0.f);
  const float* base = prev + (size_t)b * LL * DD + 4 * t;
#pragma unroll 4
  for (int l = l0; l < l1; ++l) {
    const float4 v = *(const float4*)(base + (size_t)l * DD);
    acc.x += v.x; acc.y += v.y; acc.z += v.z; acc.w += v.w;
  }
  float4* dst = (float4*)(P + ((size_t)s * BB + b) * DD) + t;
  *dst = acc;  // unconditional: inactive splits write zeros
}

// ---------------------------------------------------------------------------
// Kernel 2: reduce P over splits -> emb[b][d] = sum / pool_len.
// grid = B, block = 320 (thread t owns float4 #t of emb[b]). Also initializes
// out[b] = cls_b (kernel 3 accumulates into it with atomics).
// ---------------------------------------------------------------------------
__global__ __launch_bounds__(320) void emb_reduce(
    const float* __restrict__ P, const int* __restrict__ lengths,
    const float* __restrict__ cls_b, float* __restrict__ emb,
    float* __restrict__ out) {
  const int b = blockIdx.x;
  const int t = threadIdx.x;

  const float inv = 1.0f / (float)(lengths[b] + 2);
  float4 acc = make_float4(0.f, 0.f, 0.f, 0.f);
#pragma unroll
  for (int s = 0; s < SPLITS; ++s) {
    const float4 v = *((const float4*)(P + ((size_t)s * BB + b) * DD) + t);
    acc.x += v.x; acc.y += v.y; acc.z += v.z; acc.w += v.w;
  }
  acc.x *= inv; acc.y *= inv; acc.z *= inv; acc.w *= inv;
  *((float4*)(emb + (size_t)b * DD) + t) = acc;
  if (t == 0) out[b] = cls_b[0];
}

// ---------------------------------------------------------------------------
// Kernel 3: per (b, col): relu(emb[b]·W[:,col] + bias[col]) * cls_w[col],
// reduced over cols into out[b] via one atomicAdd per wave.
// grid = (CC, BG), block = 256 = 4 waves. Wave w handles b = bg*4+w over the
// same 64 cols -> all 4 waves load identical W lines (L1 broadcast), cutting
// W L2/LLC traffic 4x vs one-b-per-block. emb rows staged in LDS (broadcast
// reads, conflict-free). unroll 16 keeps 16 W loads in flight per lane.
// ---------------------------------------------------------------------------
__global__ __launch_bounds__(256) void gemm_relu_out(
    const float* __restrict__ emb, const float* __restrict__ W,
    const float* __restrict__ bias, const float* __restrict__ cls_w,
    float* __restrict__ out) {
  __shared__ float es[4 * DD];

  const int cc = blockIdx.x;
  const int bg = blockIdx.y;
  const int t = threadIdx.x;
  const int lane = t & 63;
  const int wave = t >> 6;          // 0..3 -> which b
  const int b = bg * 4 + wave;
  const int col = cc * 64 + lane;

  // Stage 4 emb rows (4*1280 floats) into LDS, coalesced.
  const float* eg = emb + (size_t)bg * 4 * DD;
  for (int i = t; i < 4 * DD; i += 256) es[i] = eg[i];
  __syncthreads();

  const float* ew = es + wave * DD;
  const float* wp = W + col;
  float acc = bias[col];
#pragma unroll 16
  for (int d = 0; d < DD; ++d) {
    acc = fmaf(ew[d], wp[(size_t)d * DD], acc);
  }
  float v = fmaxf(acc, 0.f) * cls_w[col];

  // Wave-level reduction over the 64 cols.
#pragma unroll
  for (int off = 32; off > 0; off >>= 1) v += __shfl_down(v, off);
  if (lane == 0) atomicAdd(out + b, v);
}

extern "C" void kernel_launch(void* const* d_in, const int* in_sizes, int n_in,
                              void* d_out, int out_size, void* d_ws, size_t ws_size,
                              hipStream_t stream) {
  const float* prev    = (const float*)d_in[0];  // [B, L, D] f32
  const int*   lengths = (const int*)d_in[1];    // [B] i32
  const float* dense_w = (const float*)d_in[2];  // [D, D] f32
  const float* dense_b = (const float*)d_in[3];  // [D] f32
  const float* cls_w   = (const float*)d_in[4];  // [D, 1] f32
  const float* cls_b   = (const float*)d_in[5];  // [1] f32
  float* out = (float*)d_out;                    // [B] f32

  // Workspace: P [SPLITS*B*D] floats (5.24 MB), emb [B*D] floats (327 KB).
  float* P = (float*)d_ws;
  float* emb = P + (size_t)SPLITS * BB * DD;

  pool_partial<<<dim3(SPLITS, BB), 320, 0, stream>>>(prev, lengths, P);
  emb_reduce<<<BB, 320, 0, stream>>>(P, lengths, cls_b, emb, out);
  gemm_relu_out<<<dim3(CC, BG), 256, 0, stream>>>(emb, dense_w, dense_b,
                                                  cls_w, out);
}

// Round 3
// 457.651 us; speedup vs baseline: 1.0902x; 1.0366x over previous
//
#include <hip/hip_runtime.h>

// Problem constants (reference: B=64, L=1024, D=1280)
#define BB 64
#define LL 1024
#define DD 1280
#define SPLITS 32       // token splits for the pool
#define CHUNK 32        // L / SPLITS
#define CC 20           // column chunks of 64 (20*64 = 1280)
#define BG 16           // b-groups of 4 (16*4 = 64)

// ---------------------------------------------------------------------------
// Kernel 1: ragged partial sum pool, pre-scaled by 1/pool_len (distributive:
// sum_s(partial_s)/n == sum_s(partial_s/n)), so kernel 2 is a pure sum.
// grid = (SPLITS, B) = 2048 blocks, block = 320 threads (5 waves) -> 6
// blocks/CU = 30 waves/CU for HBM latency hiding. Thread t owns float4 #t of
// each 1280-float row; one block iteration reads one full row (5120 B),
// coalesced 16 B/lane. Inactive splits write zeros (no ws pre-zero needed).
// ---------------------------------------------------------------------------
__global__ __launch_bounds__(320) void pool_partial(
    const float* __restrict__ prev, const int* __restrict__ lengths,
    float* __restrict__ P) {
  const int s = blockIdx.x;
  const int b = blockIdx.y;
  const int t = threadIdx.x;  // [0, 320)

  const int pool_len = lengths[b] + 2;  // in [2, 1023]
  const float inv = 1.0f / (float)pool_len;
  const int l0 = s * CHUNK;
  const int l1 = min(pool_len, l0 + CHUNK);

  float4 acc = make_float4(0.f, 0.f, 0.f, 0.f);
  const float* base = prev + (size_t)b * LL * DD + 4 * t;
#pragma unroll 4
  for (int l = l0; l < l1; ++l) {
    const float4 v = *(const float4*)(base + (size_t)l * DD);
    acc.x += v.x; acc.y += v.y; acc.z += v.z; acc.w += v.w;
  }
  acc.x *= inv; acc.y *= inv; acc.z *= inv; acc.w *= inv;
  float4* dst = (float4*)(P + ((size_t)s * BB + b) * DD) + t;
  *dst = acc;  // unconditional: inactive splits write zeros
}

// ---------------------------------------------------------------------------
// Kernel 2: emb[b][d] = sum_s P[s][b][d] (already scaled). Also initializes
// out[b] = cls_b (kernel 3 accumulates into it with atomics).
// grid = B, block = 320 (thread t owns float4 #t of emb[b]).
// ---------------------------------------------------------------------------
__global__ __launch_bounds__(320) void emb_reduce(
    const float* __restrict__ P, const float* __restrict__ cls_b,
    float* __restrict__ emb, float* __restrict__ out) {
  const int b = blockIdx.x;
  const int t = threadIdx.x;

  float4 acc = make_float4(0.f, 0.f, 0.f, 0.f);
#pragma unroll
  for (int s = 0; s < SPLITS; ++s) {
    const float4 v = *((const float4*)(P + ((size_t)s * BB + b) * DD) + t);
    acc.x += v.x; acc.y += v.y; acc.z += v.z; acc.w += v.w;
  }
  *((float4*)(emb + (size_t)b * DD) + t) = acc;
  if (t == 0) out[b] = cls_b[0];
}

// ---------------------------------------------------------------------------
// Kernel 3: per (b, col): relu(emb[b]·W[:,col] + bias[col]) * cls_w[col],
// reduced over cols into out[b] via one atomicAdd per wave.
// grid = (CC, BG) = 320 blocks (1.25/CU -> every CU busy), block = 256 = 4
// waves. Wave w handles b = bg*4+w over the same 64 cols -> all 4 waves load
// identical W lines (L1 broadcast), 4x W-reuse. emb rows staged in LDS
// (broadcast reads, conflict-free). unroll 32 keeps 32 W loads in flight per
// lane: ~1280/32 * 220 cyc latency-bound loop.
// ---------------------------------------------------------------------------
__global__ __launch_bounds__(256) void gemm_relu_out(
    const float* __restrict__ emb, const float* __restrict__ W,
    const float* __restrict__ bias, const float* __restrict__ cls_w,
    float* __restrict__ out) {
  __shared__ float es[4 * DD];

  const int cc = blockIdx.x;
  const int bg = blockIdx.y;
  const int t = threadIdx.x;
  const int lane = t & 63;
  const int wave = t >> 6;          // 0..3 -> which b
  const int b = bg * 4 + wave;
  const int col = cc * 64 + lane;

  // Stage 4 emb rows (4*1280 floats) into LDS, coalesced.
  const float* eg = emb + (size_t)bg * 4 * DD;
  for (int i = t; i < 4 * DD; i += 256) es[i] = eg[i];
  __syncthreads();

  const float* ew = es + wave * DD;
  const float* wp = W + col;
  float acc = bias[col];
#pragma unroll 32
  for (int d = 0; d < DD; ++d) {
    acc = fmaf(ew[d], wp[(size_t)d * DD], acc);
  }
  float v = fmaxf(acc, 0.f) * cls_w[col];

  // Wave-level reduction over the 64 cols.
#pragma unroll
  for (int off = 32; off > 0; off >>= 1) v += __shfl_down(v, off);
  if (lane == 0) atomicAdd(out + b, v);
}

extern "C" void kernel_launch(void* const* d_in, const int* in_sizes, int n_in,
                              void* d_out, int out_size, void* d_ws, size_t ws_size,
                              hipStream_t stream) {
  const float* prev    = (const float*)d_in[0];  // [B, L, D] f32
  const int*   lengths = (const int*)d_in[1];    // [B] i32
  const float* dense_w = (const float*)d_in[2];  // [D, D] f32
  const float* dense_b = (const float*)d_in[3];  // [D] f32
  const float* cls_w   = (const float*)d_in[4];  // [D, 1] f32
  const float* cls_b   = (const float*)d_in[5];  // [1] f32
  float* out = (float*)d_out;                    // [B] f32

  // Workspace: P [SPLITS*B*D] floats (10.5 MB), emb [B*D] floats (327 KB).
  float* P = (float*)d_ws;
  float* emb = P + (size_t)SPLITS * BB * DD;

  pool_partial<<<dim3(SPLITS, BB), 320, 0, stream>>>(prev, lengths, P);
  emb_reduce<<<BB, 320, 0, stream>>>(P, cls_b, emb, out);
  gemm_relu_out<<<dim3(CC, BG), 256, 0, stream>>>(emb, dense_w, dense_b,
                                                  cls_w, out);
}